// Round 5
// baseline (212.880 us; speedup 1.0000x reference)
//
#include <hip/hip_runtime.h>
#include <hip/hip_bf16.h>
#include <math.h>

// Problem constants
#define MTOT   8192        // B*T
#define KDIM   1024        // IN_DIMS
#define NCODES 1024
#define NCB    8
#define NTOT   8192        // NUM_CODEBOOKS*NUM_CODES
#define ODIM   1024

typedef __attribute__((ext_vector_type(8))) short  bf16x8;
typedef __attribute__((ext_vector_type(4))) float  f32x4;

__device__ __forceinline__ ushort f2bf(float f) {
  union { float f; unsigned u; } v; v.f = f;
  unsigned u = v.u;
  unsigned r = (u + 0x7fffu + ((u >> 16) & 1u)) >> 16;  // RNE
  return (ushort)r;
}

__device__ __forceinline__ void gload16(const void* g, void* l) {
  __builtin_amdgcn_global_load_lds(
      (const __attribute__((address_space(1))) void*)g,
      (__attribute__((address_space(3))) void*)l,
      16, 0, 0);
}

// ---------------- Kernel A: f32 -> bf16 convert (proj_w) ----------------
__global__ void cvt_bf16_kernel(const float* __restrict__ in,
                                ushort* __restrict__ out) {
  int i = blockIdx.x * blockDim.x + threadIdx.x;   // one float4 per thread
  float4 v = ((const float4*)in)[i];
  ushort4 o;
  o.x = f2bf(v.x); o.y = f2bf(v.y); o.z = f2bf(v.z); o.w = f2bf(v.w);
  ((ushort4*)out)[i] = o;
}

// ------------- Kernel B: persistent 2-barrier/K-tile GEMM + fused CE loss --
// One block per (mtile, codebook): 64 global K-tiles = 4 segments x 16.
// Per K-tile: issue ALL 24 ds_reads (A0,B0,B1,A1) up front; MFMA quadrants
// consume them under compiler-emitted counted lgkmcnt -> LDS drain overlaps
// the MFMA stream (the per-quadrant-barrier structure forced them to
// alternate -> 35% MfmaUtil ceiling). Staging WAR discipline:
//   - stage(t+1).Ah1 issues in tile-t 1st half (its region's readers all
//     completed before the t-1->t boundary barrier)
//   - stage(t+2).{Ah0,Bh0,Bh1} issues after the mid-barrier (those regions'
//     reads completed before each wave's q0/q1 MFMA lgkm wait; q3 uses B0
//     from REGISTERS, not LDS)
//   - boundary: s_waitcnt vmcnt(6) (counted, never 0 in steady state)

__device__ __forceinline__ void chunk_dec(int c, int& srcA, int& srcB) {
  const int q  = c >> 6;                 // subtile index within half (0..15)
  const int sq = q >> 1;                 // 0..7
  const int ct = q & 1;                  // k-half of subtile (32 cols each)
  const int r4 = (c >> 2) & 15;
  const int cb = (((c & 3) ^ ((c >> 3) & 3)) << 4);  // inverse-swizzled src col
  const int rtA = (sq & 3) + ((sq >> 2) << 3);       // h=0 row-tile
  const int rtB = (sq & 1) + ((sq >> 1) << 2);       // h=0 row-tile
  srcA = ((rtA << 4) + r4) * (KDIM * 2) + ct * 64 + cb;
  srcB = ((rtB << 4) + r4) * (KDIM * 2) + ct * 64 + cb;
}

#define STAGE_A(T, H) do { \
    const int ao_ = (((T) & 15) * 128 + (H) * 131072); \
    char* ld_ = ldsA_st + ((T) & 1) * 32768 + (H) * 16384; \
    gload16(Ag + (size_t)(srcA0 + ao_), ld_); \
    gload16(Ag + (size_t)(srcA1 + ao_), ld_ + 8192); \
  } while(0)
#define STAGE_B(T, H) do { \
    const int bo_ = (((T) >> 4) * 524288 + ((T) & 15) * 128 + (H) * 65536); \
    char* ld_ = ldsB_st + ((T) & 1) * 32768 + (H) * 16384; \
    gload16(Bg + (size_t)(srcB0 + bo_), ld_); \
    gload16(Bg + (size_t)(srcB1 + bo_), ld_ + 8192); \
  } while(0)

#define LDA_Q(P, MH, AR) do { \
    _Pragma("unroll") for (int m_ = 0; m_ < 4; ++m_) \
    _Pragma("unroll") for (int k_ = 0; k_ < 2; ++k_) \
      AR[m_][k_] = *(const bf16x8*)(ldsA_rd + (P)*32768 + (MH)*16384 + m_*2048 + k_*1024); \
  } while(0)
#define LDB_Q(P, NH, BR) do { \
    _Pragma("unroll") for (int n_ = 0; n_ < 2; ++n_) \
    _Pragma("unroll") for (int k_ = 0; k_ < 2; ++k_) \
      BR[n_][k_] = *(const bf16x8*)(ldsB_rd + (P)*32768 + (NH)*16384 + n_*2048 + k_*1024); \
  } while(0)
#define MM_Q(MH, NH, AR, BR) do { \
    _Pragma("unroll") for (int k_ = 0; k_ < 2; ++k_) \
    _Pragma("unroll") for (int m_ = 0; m_ < 4; ++m_) \
    _Pragma("unroll") for (int n_ = 0; n_ < 2; ++n_) \
      acc[(MH)*4+m_][(NH)*2+n_] = __builtin_amdgcn_mfma_f32_16x16x32_bf16( \
          AR[m_][k_], BR[n_][k_], acc[(MH)*4+m_][(NH)*2+n_], 0, 0, 0); \
  } while(0)

// Per-segment flush: bias + exp-sum (fixed M=0; logits bounded) + target
// logit extraction. asm barriers only -> staging vmcnt pipeline survives.
#define FLUSH(SEG) do { \
    const int colb_ = (SEG) * 256 + wc * 64; \
    float bias_n[4]; \
    _Pragma("unroll") for (int n_ = 0; n_ < 4; ++n_) \
      bias_n[n_] = bias[kcb * 1024 + colb_ + n_ * 16 + c15]; \
    _Pragma("unroll") for (int m_ = 0; m_ < 8; ++m_) { \
      _Pragma("unroll") for (int j_ = 0; j_ < 4; ++j_) { \
        const int rl_ = wr * 128 + m_ * 16 + g * 4 + j_; \
        const int tc_ = tgtcol[rl_]; \
        float s_ = 0.f; \
        _Pragma("unroll") for (int n_ = 0; n_ < 4; ++n_) { \
          const float v_ = acc[m_][n_][j_] + bias_n[n_]; \
          if (colb_ + n_ * 16 + c15 == tc_) tgtval[rl_] = v_; \
          s_ += __expf(v_); \
        } \
        _Pragma("unroll") for (int o_ = 1; o_ < 16; o_ <<= 1) \
          s_ += __shfl_xor(s_, o_); \
        if (c15 == 0) redS[wc * 256 + rl_] = s_; \
      } \
    } \
    asm volatile("s_waitcnt lgkmcnt(0)" ::: "memory"); \
    asm volatile("s_barrier" ::: "memory"); \
    if (tid < 256) \
      S_acc += redS[tid] + redS[tid + 256] + redS[tid + 512] + redS[tid + 768]; \
    _Pragma("unroll") for (int m_ = 0; m_ < 8; ++m_) \
      _Pragma("unroll") for (int n_ = 0; n_ < 4; ++n_) \
        acc[m_][n_] = (f32x4){0.f, 0.f, 0.f, 0.f}; \
  } while(0)

__global__ __launch_bounds__(512, 2)
void ce_gemm_kernel(const ushort* __restrict__ Abf,   // [8192][1024] x (bf16)
                    const ushort* __restrict__ Bbf,   // [8192][1024] proj_w (bf16)
                    const float*  __restrict__ bias,  // [8192]
                    const int*    __restrict__ target,// [8192][8]
                    float* __restrict__ xloss) {      // [8192][8]
  extern __shared__ char smem[];
  float* redS   = (float*)(smem + 131072);   // [4][256]
  int*   tgtcol = (int*)  (smem + 135168);   // [256]
  float* tgtval = (float*)(smem + 136192);   // [256]

  const int tid  = threadIdx.x;
  const int wid  = tid >> 6;
  const int lane = tid & 63;
  const int wr   = wid >> 2;       // wave row (0..1) -> rows wr*128
  const int wc   = wid & 3;        // wave col (0..3) -> cols wc*64
  const int g    = lane >> 4;
  const int c15  = lane & 15;
  // XCD-locality swizzle: XCD = blockIdx.x % 8 owns mtiles 4x..4x+3, all kcbs
  const int bidx  = blockIdx.x;
  const int u     = bidx >> 3;
  const int mtile = (bidx & 7) * 4 + (u & 3);   // 32 mtiles
  const int kcb   = u >> 2;                     // 8 codebooks

  // per-lane swizzled LDS read offset (16B aligned)
  const int swz = (c15 * 64 + g * 16) ^ ((c15 & 6) << 3);
  const char* ldsA_rd = smem + wr * 8192 + swz;
  const char* ldsB_rd = smem + 65536 + wc * 4096 + swz;
  char* ldsA_st = smem + wid * 1024;            // wave-uniform; HW adds lane*16
  char* ldsB_st = smem + 65536 + wid * 1024;

  const char* Ag = ((const char*)Abf) + (size_t)mtile * 256 * (KDIM * 2);
  const char* Bg = ((const char*)Bbf) + (size_t)kcb * 2097152;  // 4x256 rows
  int srcA0, srcB0, srcA1, srcB1;
  chunk_dec(tid,       srcA0, srcB0);
  chunk_dec(tid + 512, srcA1, srcB1);

  // block-local target columns (one codebook per block)
  if (tid < 256)
    tgtcol[tid] = target[(size_t)(mtile * 256 + tid) * NCB + kcb];

  f32x4 acc[8][4];
#pragma unroll
  for (int m = 0; m < 8; ++m)
#pragma unroll
    for (int n = 0; n < 4; ++n)
      acc[m][n] = (f32x4){0.f, 0.f, 0.f, 0.f};

  float S_acc = 0.f;
  bf16x8 a0[4][2], a1[4][2], b0[2][2], b1[2][2];

  // ---- prologue: tile0 fully + tile1 {Ah0, Bh0, Bh1}; Ah1(1) joins in t=0
  STAGE_A(0, 0); STAGE_A(0, 1); STAGE_B(0, 0); STAGE_B(0, 1);
  STAGE_A(1, 0); STAGE_B(1, 0); STAGE_B(1, 1);
  asm volatile("s_waitcnt vmcnt(6)" ::: "memory");
  __syncthreads();   // one-time full drain; also orders tgtcol writes

  // ---- main loop: one K-tile per iteration, 2 barriers per tile
#pragma unroll 1
  for (int t = 0; t < 64; ++t) {
    const int P = t & 1;
    // -- 1st half: ALL ds_reads for tile t, then q0,q1 (compiler counted-lgkm)
    LDA_Q(P, 0, a0); LDB_Q(P, 0, b0); LDB_Q(P, 1, b1); LDA_Q(P, 1, a1);
    if (t < 63) STAGE_A(t + 1, 1);
    __builtin_amdgcn_s_setprio(1);
    MM_Q(0, 0, a0, b0);
    MM_Q(0, 1, a0, b1);
    __builtin_amdgcn_s_setprio(0);
    asm volatile("s_barrier" ::: "memory");          // mid (WAR fence)
    // -- 2nd half: stage t+2 into regions whose tile-t reads are complete
    if (t < 62) { STAGE_A(t + 2, 0); STAGE_B(t + 2, 0); STAGE_B(t + 2, 1); }
    __builtin_amdgcn_s_setprio(1);
    MM_Q(1, 1, a1, b1);
    MM_Q(1, 0, a1, b0);                              // B0 from regs, not LDS
    __builtin_amdgcn_s_setprio(0);
    if (t < 62) { asm volatile("s_waitcnt vmcnt(6)" ::: "memory"); }
    else        { asm volatile("s_waitcnt vmcnt(0)" ::: "memory"); }
    asm volatile("s_barrier" ::: "memory");          // boundary
    if ((t & 15) == 15) FLUSH(t >> 4);
  }

  __syncthreads();
  if (tid < 256) {
    const int row = mtile * 256 + tid;
    xloss[(size_t)row * NCB + kcb] = __logf(S_acc) - tgtval[tid];
  }
}

// ------------- Kernel D: xw softmax + codebook gather -> emb (+x->bf16) ----
__global__ void emb_kernel(const float* __restrict__ x,
                           const int*   __restrict__ target,
                           const float* __restrict__ cb,       // [1024][8][1024]
                           const float* __restrict__ wproj,    // [8][1024]
                           float* __restrict__ emb_out,
                           ushort* __restrict__ xbf) {
  const int bt   = blockIdx.x;
  const int tid  = threadIdx.x;
  const int lane = tid & 63;
  const int wid  = tid >> 6;

  const float4 xv = ((const float4*)(x + (size_t)bt * KDIM))[tid];
  // fused x -> bf16 (feeds ce_gemm; saves a separate pass over x)
  ushort4 xo;
  xo.x = f2bf(xv.x); xo.y = f2bf(xv.y); xo.z = f2bf(xv.z); xo.w = f2bf(xv.w);
  ((ushort4*)(xbf + (size_t)bt * KDIM))[tid] = xo;

  float p[8];
#pragma unroll
  for (int k = 0; k < 8; ++k) {
    const float4 wv = ((const float4*)(wproj + k * KDIM))[tid];
    p[k] = xv.x * wv.x + xv.y * wv.y + xv.z * wv.z + xv.w * wv.w;
  }
#pragma unroll
  for (int k = 0; k < 8; ++k)
#pragma unroll
    for (int off = 32; off >= 1; off >>= 1)
      p[k] += __shfl_xor(p[k], off);

  __shared__ float lred[4][8];
  if (lane == 0) {
#pragma unroll
    for (int k = 0; k < 8; ++k) lred[wid][k] = p[k];
  }
  __syncthreads();

  float logit[8], mx = -1e30f;
#pragma unroll
  for (int k = 0; k < 8; ++k) {
    logit[k] = lred[0][k] + lred[1][k] + lred[2][k] + lred[3][k];
    mx = fmaxf(mx, logit[k]);
  }
  float w[8], den = 0.f;
#pragma unroll
  for (int k = 0; k < 8; ++k) { w[k] = __expf(logit[k] - mx); den += w[k]; }
  const float inv = 1.f / den;

  float4 acc = make_float4(0.f, 0.f, 0.f, 0.f);
#pragma unroll
  for (int k = 0; k < 8; ++k) {
    const int t = target[bt * NCB + k];
    const float4 cv = ((const float4*)(cb + ((size_t)t * NCB + k) * ODIM))[tid];
    const float wk = w[k] * inv;
    acc.x += wk * cv.x; acc.y += wk * cv.y; acc.z += wk * cv.z; acc.w += wk * cv.w;
  }
  ((float4*)(emb_out + (size_t)bt * ODIM))[tid] = acc;
}

// ---------------------------------------------------------------------------
extern "C" void kernel_launch(void* const* d_in, const int* in_sizes, int n_in,
                              void* d_out, int out_size, void* d_ws, size_t ws_size,
                              hipStream_t stream) {
  const float* x        = (const float*)d_in[0];
  const int*   target   = (const int*)  d_in[1];
  const float* codebook = (const float*)d_in[2];
  const float* proj_w   = (const float*)d_in[3];
  const float* proj_b   = (const float*)d_in[4];
  const float* wproj_w  = (const float*)d_in[5];

  float* out       = (float*)d_out;
  float* emb_out   = out;                          // 8M f32
  float* xloss_out = out + (size_t)MTOT * ODIM;    // 64K f32

  char* ws = (char*)d_ws;
  ushort* xbf = (ushort*)ws;                               // 16 MB
  ushort* wbf = (ushort*)(ws + (size_t)16 * 1024 * 1024);  // 16 MB

  hipFuncSetAttribute((const void*)ce_gemm_kernel,
                      hipFuncAttributeMaxDynamicSharedMemorySize, 137216);

  // D first: produces xbf (and emb), then proj_w cvt, then the big fused GEMM
  emb_kernel<<<MTOT, 256, 0, stream>>>(x, target, codebook, wproj_w, emb_out, xbf);
  cvt_bf16_kernel<<<(NTOT * KDIM / 4) / 256, 256, 0, stream>>>(proj_w, wbf);

  ce_gemm_kernel<<<256, 512, 137216, stream>>>(xbf, wbf, proj_b, target, xloss_out);
}